// Round 3
// baseline (9807.180 us; speedup 1.0000x reference)
//
#include <hip/hip_runtime.h>
#include <math.h>

typedef _Float16 f16;
typedef __attribute__((ext_vector_type(4))) _Float16 f16x4;
typedef __attribute__((ext_vector_type(4))) float f32x4;

#define NW 4096
#define TC 32768
#define CCH 128
#define CWU 64
#define BCH 64
#define BWU 64

static __device__ __forceinline__ float sigm(float x){ return 1.0f/(1.0f + expf(-x)); }

// ---------- elementwise helpers ----------
__global__ void k_conv(const float* __restrict__ s, f16* __restrict__ d, int n){
  int i = blockIdx.x*256 + threadIdx.x;
  if (i < n) d[i] = (f16)s[i];
}

// W [G][H] f32 -> o [H][G] f16   (transposed recurrent weights)
__global__ void k_trans(const float* __restrict__ W, f16* __restrict__ o, int G, int H){
  int i = blockIdx.x*256 + threadIdx.x;
  if (i < G*H){ int g = i/H, k = i - g*H; o[(size_t)k*G + g] = (f16)W[i]; }
}

__global__ void k_fill_inv(int* inv){ int i = blockIdx.x*256 + threadIdx.x; if (i < TC) inv[i] = -1; }
__global__ void k_set_inv(const int* __restrict__ we, int* __restrict__ inv){
  int i = blockIdx.x*256 + threadIdx.x; if (i < NW) inv[we[i]] = i;
}

// ---------- generic f16 MFMA GEMM: C[M,N] = act(A[M,K] @ B[N,K]^T + bias[N]) ----------
// act: 0=none 1=relu 2=leaky(0.01).  C row stride ldc, column offset coff.
__global__ __launch_bounds__(256) void k_gemm(
    const f16* __restrict__ A, const f16* __restrict__ B, float* __restrict__ C,
    const float* __restrict__ bias, int M, int N, int K, int ldc, int coff, int act)
{
  __shared__ f16 As[64][40];
  __shared__ f16 Bs[64][40];
  const int tid = threadIdx.x;
  const int row0 = blockIdx.y*64, col0 = blockIdx.x*64;
  const int w = tid>>6, lane = tid&63, wr = w>>1, wc = w&1;
  const int lr = tid>>2, lk = (tid&3)*8;
  f32x4 acc[2][2];
  for (int a=0;a<2;a++) for(int b=0;b<2;b++) acc[a][b] = (f32x4){0.f,0.f,0.f,0.f};
  const int nkt = (K+31)>>5;
  for (int kt=0; kt<nkt; ++kt){
    const int kb = (kt<<5) + lk;
    {
      int gr = row0 + lr;
      if (gr < M && kb + 8 <= K){
        f16x4 v0 = *(const f16x4*)(A + (size_t)gr*K + kb);
        f16x4 v1 = *(const f16x4*)(A + (size_t)gr*K + kb + 4);
        *(f16x4*)&As[lr][lk] = v0; *(f16x4*)&As[lr][lk+4] = v1;
      } else {
        for (int j=0;j<8;j++){ int kk = kb+j; As[lr][lk+j] = (gr<M && kk<K) ? A[(size_t)gr*K+kk] : (f16)0.f; }
      }
      int gc = col0 + lr;
      if (gc < N && kb + 8 <= K){
        f16x4 v0 = *(const f16x4*)(B + (size_t)gc*K + kb);
        f16x4 v1 = *(const f16x4*)(B + (size_t)gc*K + kb + 4);
        *(f16x4*)&Bs[lr][lk] = v0; *(f16x4*)&Bs[lr][lk+4] = v1;
      } else {
        for (int j=0;j<8;j++){ int kk = kb+j; Bs[lr][lk+j] = (gc<N && kk<K) ? B[(size_t)gc*K+kk] : (f16)0.f; }
      }
    }
    __syncthreads();
    #pragma unroll
    for (int kk=0; kk<32; kk+=16){
      const int kq = kk + (lane>>4)*4;
      f16x4 af[2], bf[2];
      af[0] = *(const f16x4*)&As[wr*32 +      (lane&15)][kq];
      af[1] = *(const f16x4*)&As[wr*32 + 16 + (lane&15)][kq];
      bf[0] = *(const f16x4*)&Bs[wc*32 +      (lane&15)][kq];
      bf[1] = *(const f16x4*)&Bs[wc*32 + 16 + (lane&15)][kq];
      #pragma unroll
      for (int mt=0;mt<2;mt++)
        #pragma unroll
        for (int nt=0;nt<2;nt++)
          acc[mt][nt] = __builtin_amdgcn_mfma_f32_16x16x16f16(af[mt], bf[nt], acc[mt][nt], 0,0,0);
    }
    __syncthreads();
  }
  for (int mt=0;mt<2;mt++) for (int nt=0;nt<2;nt++){
    int c = col0 + wc*32 + nt*16 + (lane&15);
    if (c >= N) continue;
    float bv = bias ? bias[c] : 0.f;
    for (int j=0;j<4;j++){
      int r = row0 + wr*32 + mt*16 + (lane>>4)*4 + j;
      if (r >= M) continue;
      float v = acc[mt][nt][j] + bv;
      if (act==1) v = v>0.f ? v : 0.f;
      else if (act==2) v = v>0.f ? v : 0.01f*v;
      C[(size_t)r*ldc + coff + c] = v;
    }
  }
}

// ---------- chunked char LSTM (gate table T5[vocab][800], streamed Whh^T f16) ----------
__global__ __launch_bounds__(256) void k_charlstm(
    const float* __restrict__ T5, const int* __restrict__ cid,
    const f16* __restrict__ WT, const int* __restrict__ inv, float* __restrict__ hend)
{
  __shared__ float hs[200], cs[200], gs[800];
  const int tid = threadIdx.x;
  const int start = blockIdx.x * CCH;
  const int t0 = (start >= CWU) ? start - CWU : 0;
  const int tend = start + CCH;
  for (int i=tid;i<200;i+=256){ hs[i]=0.f; cs[i]=0.f; }
  __syncthreads();
  const int g0 = tid*4;
  const bool on = (tid < 200);
  for (int t=t0; t<tend; ++t){
    const int row = cid[t];
    if (on){
      float4 a = *(const float4*)&T5[(size_t)row*800 + g0];
      for (int k=0;k<200;k++){
        float hk = hs[k];
        f16x4 w = *(const f16x4*)&WT[(size_t)k*800 + g0];
        a.x += (float)w[0]*hk; a.y += (float)w[1]*hk;
        a.z += (float)w[2]*hk; a.w += (float)w[3]*hk;
      }
      *(float4*)&gs[g0] = a;
    }
    __syncthreads();
    if (on){
      float c = sigm(gs[200+tid]) * cs[tid] + sigm(gs[tid]) * tanhf(gs[400+tid]);
      cs[tid] = c;
      float h = sigm(gs[600+tid]) * tanhf(c);
      hs[tid] = h;
      if (t >= start){ int wi = inv[t]; if (wi >= 0) hend[(size_t)wi*200 + tid] = h; }
    }
    __syncthreads();
  }
}

// ---------- chunked biLSTM layer (both directions via blockIdx.y) ----------
__global__ __launch_bounds__(512) void k_bilstm(
    const float* __restrict__ xgF, const float* __restrict__ xgB,
    const f16* __restrict__ WTF, const f16* __restrict__ WTB,
    float* __restrict__ hout)
{
  __shared__ float hs[400], cs[400], gs[1600];
  const int tid = threadIdx.x;
  const int d = blockIdx.y;
  const float* __restrict__ xg = d ? xgB : xgF;
  const f16* __restrict__ WT = d ? WTB : WTF;
  const int start = blockIdx.x * BCH;
  const int t0 = (start >= BWU) ? start - BWU : 0;
  const int tend = start + BCH;
  for (int i=tid;i<400;i+=512){ hs[i]=0.f; cs[i]=0.f; }
  __syncthreads();
  const int g0 = tid*4;
  const bool on = (tid < 400);
  for (int p=t0; p<tend; ++p){
    const int q = d ? (NW-1-p) : p;
    if (on){
      float4 a = *(const float4*)&xg[(size_t)q*1600 + g0];
      for (int k=0;k<400;k++){
        float hk = hs[k];
        f16x4 w = *(const f16x4*)&WT[(size_t)k*1600 + g0];
        a.x += (float)w[0]*hk; a.y += (float)w[1]*hk;
        a.z += (float)w[2]*hk; a.w += (float)w[3]*hk;
      }
      *(float4*)&gs[g0] = a;
    }
    __syncthreads();
    if (on){
      float c = sigm(gs[400+tid]) * cs[tid] + sigm(gs[tid]) * tanhf(gs[800+tid]);
      cs[tid] = c;
      float h = sigm(gs[1200+tid]) * tanhf(c);
      hs[tid] = h;
      if (p >= start) hout[(size_t)q*800 + d*400 + tid] = h;
    }
    __syncthreads();
  }
}

// ---------- x0 = [word_emb[words] + h_char , tag_emb[tags]] ----------
__global__ void k_x0(const int* __restrict__ words, const int* __restrict__ tags,
                     const float* __restrict__ wemb, const float* __restrict__ temb,
                     const float* __restrict__ hch, float* __restrict__ x0)
{
  int i = blockIdx.x, tid = threadIdx.x;
  if (tid < 100) x0[(size_t)i*200 + tid] = wemb[(size_t)words[i]*100 + tid] + hch[(size_t)i*100 + tid];
  else if (tid < 200) x0[(size_t)i*200 + tid] = temb[(size_t)tags[i]*100 + (tid-100)];
}

// ---------- B1 = A@U1, av = A@u2^T ----------
__global__ __launch_bounds__(256) void k_b1av(const float* __restrict__ Ah, const float* __restrict__ U1,
    const float* __restrict__ u2, float* __restrict__ B1, float* __restrict__ av)
{
  __shared__ float u[400], uu[20];
  int tid = threadIdx.x;
  for (int i=tid;i<400;i+=256) u[i] = U1[i];
  if (tid < 20) uu[tid] = u2[tid];
  __syncthreads();
  int i = blockIdx.x*256 + tid;
  float a[20];
  for (int k=0;k<20;k++) a[k] = Ah[(size_t)i*20 + k];
  float s2 = 0.f;
  for (int k=0;k<20;k++) s2 += a[k]*uu[k];
  av[i] = s2;
  for (int j=0;j<20;j++){
    float s = 0.f;
    for (int k=0;k<20;k++) s += a[k]*u[k*20+j];
    B1[(size_t)i*20 + j] = s;
  }
}

// ---------- out[r,c] = adj.T = dot20(Dp[r], B1[c]) + av[c] ----------
__global__ __launch_bounds__(256) void k_adjT(const float* __restrict__ Dp, const float* __restrict__ B1,
    const float* __restrict__ av, float* __restrict__ out)
{
  __shared__ float Ds[64][20], Bs[64][20], avs[64];
  int tid = threadIdx.x;
  int r0 = blockIdx.y*64, c0 = blockIdx.x*64;
  for (int i=tid;i<64*20;i+=256){ int r=i/20, k=i-r*20; Ds[r][k] = Dp[(size_t)(r0+r)*20+k]; Bs[r][k] = B1[(size_t)(c0+r)*20+k]; }
  if (tid < 64) avs[tid] = av[c0+tid];
  __syncthreads();
  int tr = tid>>4, tc = tid&15;
  for (int i=0;i<4;i++){
    int r = tr*4+i;
    float4 o;
    float* op = (float*)&o;
    for (int j=0;j<4;j++){
      int c = tc*4+j;
      float s = avs[c];
      for (int k=0;k<20;k++) s += Ds[r][k]*Bs[c][k];
      op[j] = s;
    }
    *(float4*)&out[(size_t)(r0+r)*4096 + c0 + tc*4] = o;
  }
}

extern "C" void kernel_launch(void* const* d_in, const int* in_sizes, int n_in,
                              void* d_out, int out_size, void* d_ws, size_t ws_size,
                              hipStream_t stream)
{
  const int*   char_ids = (const int*)  d_in[0];
  const int*   words    = (const int*)  d_in[1];
  const int*   tags     = (const int*)  d_in[2];
  const int*   wend     = (const int*)  d_in[3];
  const float* word_emb = (const float*)d_in[4];
  const float* tag_emb  = (const float*)d_in[5];
  const float* char_emb = (const float*)d_in[6];
  const float* uni_Wih  = (const float*)d_in[7];
  const float* uni_Whh  = (const float*)d_in[8];
  const float* uni_b    = (const float*)d_in[9];
  const float* ch_W1 = (const float*)d_in[10]; const float* ch_b1 = (const float*)d_in[11];
  const float* ch_W2 = (const float*)d_in[12]; const float* ch_b2 = (const float*)d_in[13];
  const float* bWih0 = (const float*)d_in[14]; const float* bWhh0 = (const float*)d_in[15];
  const float* bb0   = (const float*)d_in[16];
  const float* bWih12= (const float*)d_in[17]; const float* bWhh12= (const float*)d_in[18];
  const float* bb12  = (const float*)d_in[19];
  const float* ah_W1 = (const float*)d_in[20]; const float* ah_b1 = (const float*)d_in[21];
  const float* ah_W2 = (const float*)d_in[22]; const float* ah_b2 = (const float*)d_in[23];
  const float* ad_W1 = (const float*)d_in[24]; const float* ad_b1 = (const float*)d_in[25];
  const float* ad_W2 = (const float*)d_in[26]; const float* ad_b2 = (const float*)d_in[27];
  const float* lh_W1 = (const float*)d_in[28]; const float* lh_b1 = (const float*)d_in[29];
  const float* lh_W2 = (const float*)d_in[30]; const float* lh_b2 = (const float*)d_in[31];
  const float* ld_W1 = (const float*)d_in[32]; const float* ld_b1 = (const float*)d_in[33];
  const float* ld_W2 = (const float*)d_in[34]; const float* ld_b2 = (const float*)d_in[35];
  const float* cl_W1 = (const float*)d_in[36]; const float* cl_b1 = (const float*)d_in[37];
  const float* cl_W2 = (const float*)d_in[38]; const float* cl_b2 = (const float*)d_in[39];
  const float* U1    = (const float*)d_in[40]; const float* u2    = (const float*)d_in[41];
  float* out = (float*)d_out;

  size_t off = 0;
  auto WS = [&](size_t bytes)->char*{ char* p = (char*)d_ws + off; off += (bytes + 255) & ~(size_t)255; return p; };
  float* T5   = (float*)WS((size_t)5000*800*4);
  float* hend = (float*)WS((size_t)4096*200*4);
  float* HW1  = (float*)WS((size_t)4096*400*4);
  float* hch  = (float*)WS((size_t)4096*100*4);
  float* x0   = (float*)WS((size_t)4096*200*4);
  float* xgF  = (float*)WS((size_t)4096*1600*4);
  float* xgB  = (float*)WS((size_t)4096*1600*4);
  float* hA   = (float*)WS((size_t)4096*800*4);
  float* hB   = (float*)WS((size_t)4096*800*4);
  int*   inv  = (int*)  WS((size_t)TC*4);
  float* headH= (float*)WS((size_t)4096*500*4);
  float* Ahd  = (float*)WS((size_t)4096*20*4);
  float* Dp   = (float*)WS((size_t)4096*20*4);
  float* LCin = (float*)WS((size_t)4096*40*4);
  float* B1   = (float*)WS((size_t)4096*20*4);
  float* av   = (float*)WS((size_t)4096*4);
  f16* Abf  = (f16*)WS((size_t)4096*800*2);
  f16* Abf2 = (f16*)WS((size_t)4096*500*2);
  f16* Bbf  = (f16*)WS((size_t)1600*800*2);
  f16* wtU  = (f16*)WS((size_t)200*800*2);
  f16* wtL[6]; for (int i=0;i<6;i++) wtL[i] = (f16*)WS((size_t)400*1600*2);

  auto conv = [&](const float* s, f16* d, int n){
    k_conv<<<dim3((n+255)/256), dim3(256), 0, stream>>>(s, d, n); };
  auto gemm = [&](const f16* A, const f16* B, float* C, const float* bias,
                  int M, int N, int K, int ldc, int coff, int act){
    k_gemm<<<dim3((unsigned)((N+63)/64), (unsigned)((M+63)/64)), dim3(256), 0, stream>>>(A,B,C,bias,M,N,K,ldc,coff,act); };

  // inverse word-end map
  k_fill_inv<<<dim3(TC/256), dim3(256), 0, stream>>>(inv);
  k_set_inv<<<dim3(NW/256), dim3(256), 0, stream>>>(wend, inv);

  // transposed f16 recurrent weights
  k_trans<<<dim3((800*200+255)/256), dim3(256), 0, stream>>>(uni_Whh, wtU, 800, 200);
  for (int l=0;l<3;l++) for (int d=0;d<2;d++){
    const float* Wp = (l==0) ? (bWhh0 + (size_t)d*1600*400)
                             : (bWhh12 + (size_t)((l-1)*2+d)*1600*400);
    k_trans<<<dim3((1600*400+255)/256), dim3(256), 0, stream>>>(Wp, wtL[l*2+d], 1600, 400);
  }

  // char gate table: T5[v] = char_emb[v] @ uni_Wih^T + uni_b
  conv(char_emb, Abf, 5000*200);
  conv(uni_Wih, Bbf, 800*200);
  gemm(Abf, Bbf, T5, uni_b, 5000, 800, 200, 800, 0, 0);

  k_charlstm<<<dim3(TC/CCH), dim3(256), 0, stream>>>(T5, char_ids, wtU, inv, hend);

  // char MLP -> h_char
  conv(hend, Abf, 4096*200); conv(ch_W1, Bbf, 400*200);
  gemm(Abf, Bbf, HW1, ch_b1, 4096, 400, 200, 400, 0, 2);
  conv(HW1, Abf, 4096*400); conv(ch_W2, Bbf, 100*400);
  gemm(Abf, Bbf, hch, ch_b2, 4096, 100, 400, 100, 0, 0);

  k_x0<<<dim3(NW), dim3(256), 0, stream>>>(words, tags, word_emb, tag_emb, hch, x0);

  // ----- biLSTM layer 0 -----
  conv(x0, Abf, 4096*200);
  conv(bWih0, Bbf, 1600*200);
  gemm(Abf, Bbf, xgF, bb0, 4096, 1600, 200, 1600, 0, 0);
  conv(bWih0 + (size_t)1600*200, Bbf, 1600*200);
  gemm(Abf, Bbf, xgB, bb0 + 1600, 4096, 1600, 200, 1600, 0, 0);
  k_bilstm<<<dim3(NW/BCH, 2), dim3(512), 0, stream>>>(xgF, xgB, wtL[0], wtL[1], hA);

  // ----- biLSTM layers 1,2 -----
  float* bufs[2] = { hA, hB };
  for (int l=1;l<3;l++){
    const float* hin = bufs[(l-1)&1];
    float* ho = bufs[l&1];
    conv(hin, Abf, 4096*800);
    conv(bWih12 + (size_t)((l-1)*2+0)*1600*800, Bbf, 1600*800);
    gemm(Abf, Bbf, xgF, bb12 + (size_t)((l-1)*2+0)*1600, 4096, 1600, 800, 1600, 0, 0);
    conv(bWih12 + (size_t)((l-1)*2+1)*1600*800, Bbf, 1600*800);
    gemm(Abf, Bbf, xgB, bb12 + (size_t)((l-1)*2+1)*1600, 4096, 1600, 800, 1600, 0, 0);
    k_bilstm<<<dim3(NW/BCH, 2), dim3(512), 0, stream>>>(xgF, xgB, wtL[l*2], wtL[l*2+1], ho);
  }
  const float* o2 = bufs[0];  // layer 2 output lands in hA

  // ----- heads -----
  conv(o2, Abf, 4096*800);
  conv(ah_W1, Bbf, 500*800); gemm(Abf, Bbf, headH, ah_b1, 4096, 500, 800, 500, 0, 1);
  conv(headH, Abf2, 4096*500); conv(ah_W2, Bbf, 20*500); gemm(Abf2, Bbf, Ahd, ah_b2, 4096, 20, 500, 20, 0, 0);
  conv(ad_W1, Bbf, 500*800); gemm(Abf, Bbf, headH, ad_b1, 4096, 500, 800, 500, 0, 1);
  conv(headH, Abf2, 4096*500); conv(ad_W2, Bbf, 20*500); gemm(Abf2, Bbf, Dp, ad_b2, 4096, 20, 500, 20, 0, 0);
  conv(lh_W1, Bbf, 200*800); gemm(Abf, Bbf, headH, lh_b1, 4096, 200, 800, 200, 0, 1);
  conv(headH, Abf2, 4096*200); conv(lh_W2, Bbf, 20*200); gemm(Abf2, Bbf, LCin, lh_b2, 4096, 20, 200, 40, 0, 0);
  conv(ld_W1, Bbf, 200*800); gemm(Abf, Bbf, headH, ld_b1, 4096, 200, 800, 200, 0, 1);
  conv(headH, Abf2, 4096*200); conv(ld_W2, Bbf, 20*200); gemm(Abf2, Bbf, LCin, ld_b2, 4096, 20, 200, 40, 20, 0);
  conv(LCin, Abf2, 4096*40); conv(cl_W1, Bbf, 60*40); gemm(Abf2, Bbf, headH, cl_b1, 4096, 60, 40, 60, 0, 1);
  conv(headH, Abf2, 4096*60); conv(cl_W2, Bbf, 40*60);
  gemm(Abf2, Bbf, out + (size_t)4096*4096, cl_b2, 4096, 40, 60, 40, 0, 0);

  // ----- biaffine adjacency (transposed) -----
  k_b1av<<<dim3(NW/256), dim3(256), 0, stream>>>(Ahd, U1, u2, B1, av);
  k_adjT<<<dim3(64,64), dim3(256), 0, stream>>>(Dp, B1, av, out);

  (void)in_sizes; (void)n_in; (void)out_size; (void)ws_size;
}

// Round 7
// 4318.382 us; speedup vs baseline: 2.2710x; 2.2710x over previous
//
#include <hip/hip_runtime.h>
#include <math.h>

typedef _Float16 f16;
typedef __attribute__((ext_vector_type(2))) _Float16 h2;
typedef __attribute__((ext_vector_type(4))) _Float16 f16x4;
typedef __attribute__((ext_vector_type(8))) _Float16 f16x8;
typedef __attribute__((ext_vector_type(4))) float f32x4;

#define NW 4096
#define TC 32768
#define CCH 64
#define CWU 48
#define BCH 32
#define BWU 48

static __device__ __forceinline__ float sigm(float x){ return 1.0f/(1.0f + expf(-x)); }

#if __has_builtin(__builtin_amdgcn_fdot2)
static __device__ __forceinline__ float DOT2(h2 w, h2 h, float acc){
  return __builtin_amdgcn_fdot2(w, h, acc, false);
}
#else
static __device__ __forceinline__ float DOT2(h2 w, h2 h, float acc){
  return fmaf((float)w[0], (float)h[0], fmaf((float)w[1], (float)h[1], acc));
}
#endif

// ---------- elementwise helpers ----------
__global__ void k_conv(const float* __restrict__ s, f16* __restrict__ d, int n){
  int i = blockIdx.x*256 + threadIdx.x;
  if (i < n) d[i] = (f16)s[i];
}

// W [G][H] f32 -> pair-interleaved: o[((k>>1)*G + g)*2 + (k&1)] = W[g][k]
__global__ void k_trans2(const float* __restrict__ W, f16* __restrict__ o, int G, int H){
  int i = blockIdx.x*256 + threadIdx.x;
  if (i < G*H){ int g = i/H, k = i - g*H; o[((size_t)(k>>1)*G + g)*2 + (k&1)] = (f16)W[i]; }
}

__global__ void k_fill_inv(int* inv){ int i = blockIdx.x*256 + threadIdx.x; if (i < TC) inv[i] = -1; }
__global__ void k_set_inv(const int* __restrict__ we, int* __restrict__ inv){
  int i = blockIdx.x*256 + threadIdx.x; if (i < NW) inv[we[i]] = i;
}

// ---------- generic f16 MFMA GEMM: C[M,N] = act(A[M,K] @ B[N,K]^T + bias[N]) ----------
__global__ __launch_bounds__(256) void k_gemm(
    const f16* __restrict__ A, const f16* __restrict__ B, float* __restrict__ C,
    const float* __restrict__ bias, int M, int N, int K, int ldc, int coff, int act)
{
  __shared__ f16 As[64][40];
  __shared__ f16 Bs[64][40];
  const int tid = threadIdx.x;
  const int row0 = blockIdx.y*64, col0 = blockIdx.x*64;
  const int w = tid>>6, lane = tid&63, wr = w>>1, wc = w&1;
  const int lr = tid>>2, lk = (tid&3)*8;
  f32x4 acc[2][2];
  for (int a=0;a<2;a++) for(int b=0;b<2;b++) acc[a][b] = (f32x4){0.f,0.f,0.f,0.f};
  const int nkt = (K+31)>>5;
  for (int kt=0; kt<nkt; ++kt){
    const int kb = (kt<<5) + lk;
    {
      int gr = row0 + lr;
      if (gr < M && kb + 8 <= K){
        f16x4 v0 = *(const f16x4*)(A + (size_t)gr*K + kb);
        f16x4 v1 = *(const f16x4*)(A + (size_t)gr*K + kb + 4);
        *(f16x4*)&As[lr][lk] = v0; *(f16x4*)&As[lr][lk+4] = v1;
      } else {
        for (int j=0;j<8;j++){ int kk = kb+j; As[lr][lk+j] = (gr<M && kk<K) ? A[(size_t)gr*K+kk] : (f16)0.f; }
      }
      int gc = col0 + lr;
      if (gc < N && kb + 8 <= K){
        f16x4 v0 = *(const f16x4*)(B + (size_t)gc*K + kb);
        f16x4 v1 = *(const f16x4*)(B + (size_t)gc*K + kb + 4);
        *(f16x4*)&Bs[lr][lk] = v0; *(f16x4*)&Bs[lr][lk+4] = v1;
      } else {
        for (int j=0;j<8;j++){ int kk = kb+j; Bs[lr][lk+j] = (gc<N && kk<K) ? B[(size_t)gc*K+kk] : (f16)0.f; }
      }
    }
    __syncthreads();
    #pragma unroll
    for (int kk=0; kk<32; kk+=16){
      const int kq = kk + (lane>>4)*4;
      f16x4 af[2], bf[2];
      af[0] = *(const f16x4*)&As[wr*32 +      (lane&15)][kq];
      af[1] = *(const f16x4*)&As[wr*32 + 16 + (lane&15)][kq];
      bf[0] = *(const f16x4*)&Bs[wc*32 +      (lane&15)][kq];
      bf[1] = *(const f16x4*)&Bs[wc*32 + 16 + (lane&15)][kq];
      #pragma unroll
      for (int mt=0;mt<2;mt++)
        #pragma unroll
        for (int nt=0;nt<2;nt++)
          acc[mt][nt] = __builtin_amdgcn_mfma_f32_16x16x16f16(af[mt], bf[nt], acc[mt][nt], 0,0,0);
    }
    __syncthreads();
  }
  for (int mt=0;mt<2;mt++) for (int nt=0;nt<2;nt++){
    int c = col0 + wc*32 + nt*16 + (lane&15);
    if (c >= N) continue;
    float bv = bias ? bias[c] : 0.f;
    for (int j=0;j<4;j++){
      int r = row0 + wr*32 + mt*16 + (lane>>4)*4 + j;
      if (r >= M) continue;
      float v = acc[mt][nt][j] + bv;
      if (act==1) v = v>0.f ? v : 0.f;
      else if (act==2) v = v>0.f ? v : 0.01f*v;
      C[(size_t)r*ldc + coff + c] = v;
    }
  }
}

// ---------- chunked char LSTM v2: R=2 chunks/block, dot2, f16 h in LDS ----------
__global__ __launch_bounds__(256) void k_charlstm2(
    const float* __restrict__ T5, const int* __restrict__ cid,
    const f16* __restrict__ WT2, const int* __restrict__ inv, float* __restrict__ hend)
{
  __shared__ f16 hsh[2][200];
  __shared__ float gs[2][800];
  const int tid = threadIdx.x;
  const int s0 = blockIdx.x * (2*CCH);
  const int s1 = s0 + CCH;
  for (int i=tid;i<200;i+=256){ hsh[0][i]=(f16)0.f; hsh[1][i]=(f16)0.f; }
  __syncthreads();
  const int g0 = tid*4;
  const bool on = (tid < 200);
  float c0r = 0.f, c1r = 0.f;
  for (int s=-CWU; s<CCH; ++s){
    const int t0 = s0 + s, t1 = s1 + s;
    const bool act0 = t0 >= 0, act1 = t1 >= 0;
    if (on){
      const int t0c = act0 ? t0 : 0, t1c = act1 ? t1 : 0;
      float4 a0 = *(const float4*)&T5[(size_t)cid[t0c]*800 + g0];
      float4 a1 = *(const float4*)&T5[(size_t)cid[t1c]*800 + g0];
      const f16* wp = WT2 + g0*2;
      #pragma unroll 4
      for (int k2=0;k2<100;k2++){
        f16x8 wv = *(const f16x8*)wp; wp += 1600;
        h2 h0 = *(const h2*)&hsh[0][k2*2];
        h2 h1 = *(const h2*)&hsh[1][k2*2];
        h2 w0 = {wv[0],wv[1]}, w1 = {wv[2],wv[3]}, w2 = {wv[4],wv[5]}, w3 = {wv[6],wv[7]};
        a0.x = DOT2(w0,h0,a0.x); a0.y = DOT2(w1,h0,a0.y); a0.z = DOT2(w2,h0,a0.z); a0.w = DOT2(w3,h0,a0.w);
        a1.x = DOT2(w0,h1,a1.x); a1.y = DOT2(w1,h1,a1.y); a1.z = DOT2(w2,h1,a1.z); a1.w = DOT2(w3,h1,a1.w);
      }
      *(float4*)&gs[0][g0] = a0;
      *(float4*)&gs[1][g0] = a1;
    }
    __syncthreads();
    if (on){
      if (act0){
        float c = sigm(gs[0][200+tid])*c0r + sigm(gs[0][tid])*tanhf(gs[0][400+tid]);
        c0r = c;
        float h = sigm(gs[0][600+tid])*tanhf(c);
        hsh[0][tid] = (f16)h;
        if (s >= 0){ int wi = inv[t0]; if (wi >= 0) hend[(size_t)wi*200 + tid] = h; }
      }
      if (act1){
        float c = sigm(gs[1][200+tid])*c1r + sigm(gs[1][tid])*tanhf(gs[1][400+tid]);
        c1r = c;
        float h = sigm(gs[1][600+tid])*tanhf(c);
        hsh[1][tid] = (f16)h;
        if (s >= 0){ int wi = inv[t1]; if (wi >= 0) hend[(size_t)wi*200 + tid] = h; }
      }
    }
    __syncthreads();
  }
}

// ---------- chunked biLSTM v2: R=2 chunks/block, dot2, f16 h in LDS ----------
__global__ __launch_bounds__(512) void k_bilstm2(
    const float* __restrict__ xgF, const float* __restrict__ xgB,
    const f16* __restrict__ WT2F, const f16* __restrict__ WT2B,
    float* __restrict__ hout)
{
  __shared__ f16 hsh[2][400];
  __shared__ float gs[2][1600];
  const int tid = threadIdx.x;
  const int d = blockIdx.y;
  const float* __restrict__ xg = d ? xgB : xgF;
  const f16* __restrict__ W2 = d ? WT2B : WT2F;
  const int s0 = blockIdx.x * (2*BCH);
  const int s1 = s0 + BCH;
  for (int i=tid;i<400;i+=512){ hsh[0][i]=(f16)0.f; hsh[1][i]=(f16)0.f; }
  __syncthreads();
  const int g0 = tid*4;
  const bool on = (tid < 400);
  float c0r = 0.f, c1r = 0.f;
  for (int s=-BWU; s<BCH; ++s){
    const int p0 = s0 + s, p1 = s1 + s;
    const bool act0 = p0 >= 0, act1 = p1 >= 0;
    const int q0 = d ? (NW-1-p0) : p0;
    const int q1 = d ? (NW-1-p1) : p1;
    if (on){
      const int q0c = act0 ? q0 : 0, q1c = act1 ? q1 : 0;
      float4 a0 = *(const float4*)&xg[(size_t)q0c*1600 + g0];
      float4 a1 = *(const float4*)&xg[(size_t)q1c*1600 + g0];
      const f16* wp = W2 + g0*2;
      #pragma unroll 4
      for (int k2=0;k2<200;k2++){
        f16x8 wv = *(const f16x8*)wp; wp += 3200;
        h2 h0 = *(const h2*)&hsh[0][k2*2];
        h2 h1 = *(const h2*)&hsh[1][k2*2];
        h2 w0 = {wv[0],wv[1]}, w1 = {wv[2],wv[3]}, w2 = {wv[4],wv[5]}, w3 = {wv[6],wv[7]};
        a0.x = DOT2(w0,h0,a0.x); a0.y = DOT2(w1,h0,a0.y); a0.z = DOT2(w2,h0,a0.z); a0.w = DOT2(w3,h0,a0.w);
        a1.x = DOT2(w0,h1,a1.x); a1.y = DOT2(w1,h1,a1.y); a1.z = DOT2(w2,h1,a1.z); a1.w = DOT2(w3,h1,a1.w);
      }
      *(float4*)&gs[0][g0] = a0;
      *(float4*)&gs[1][g0] = a1;
    }
    __syncthreads();
    if (on){
      if (act0){
        float c = sigm(gs[0][400+tid])*c0r + sigm(gs[0][tid])*tanhf(gs[0][800+tid]);
        c0r = c;
        float h = sigm(gs[0][1200+tid])*tanhf(c);
        hsh[0][tid] = (f16)h;
        if (s >= 0) hout[(size_t)q0*800 + d*400 + tid] = h;
      }
      if (act1){
        float c = sigm(gs[1][400+tid])*c1r + sigm(gs[1][tid])*tanhf(gs[1][800+tid]);
        c1r = c;
        float h = sigm(gs[1][1200+tid])*tanhf(c);
        hsh[1][tid] = (f16)h;
        if (s >= 0) hout[(size_t)q1*800 + d*400 + tid] = h;
      }
    }
    __syncthreads();
  }
}

// ---------- x0 = [word_emb[words] + h_char , tag_emb[tags]] ----------
__global__ void k_x0(const int* __restrict__ words, const int* __restrict__ tags,
                     const float* __restrict__ wemb, const float* __restrict__ temb,
                     const float* __restrict__ hch, float* __restrict__ x0)
{
  int i = blockIdx.x, tid = threadIdx.x;
  if (tid < 100) x0[(size_t)i*200 + tid] = wemb[(size_t)words[i]*100 + tid] + hch[(size_t)i*100 + tid];
  else if (tid < 200) x0[(size_t)i*200 + tid] = temb[(size_t)tags[i]*100 + (tid-100)];
}

// ---------- B1 = A@U1, av = A@u2^T ----------
__global__ __launch_bounds__(256) void k_b1av(const float* __restrict__ Ah, const float* __restrict__ U1,
    const float* __restrict__ u2, float* __restrict__ B1, float* __restrict__ av)
{
  __shared__ float u[400], uu[20];
  int tid = threadIdx.x;
  for (int i=tid;i<400;i+=256) u[i] = U1[i];
  if (tid < 20) uu[tid] = u2[tid];
  __syncthreads();
  int i = blockIdx.x*256 + tid;
  float a[20];
  for (int k=0;k<20;k++) a[k] = Ah[(size_t)i*20 + k];
  float s2 = 0.f;
  for (int k=0;k<20;k++) s2 += a[k]*uu[k];
  av[i] = s2;
  for (int j=0;j<20;j++){
    float s = 0.f;
    for (int k=0;k<20;k++) s += a[k]*u[k*20+j];
    B1[(size_t)i*20 + j] = s;
  }
}

// ---------- out[r,c] = adj.T = dot20(Dp[r], B1[c]) + av[c] ----------
__global__ __launch_bounds__(256) void k_adjT(const float* __restrict__ Dp, const float* __restrict__ B1,
    const float* __restrict__ av, float* __restrict__ out)
{
  __shared__ float Ds[64][20], Bs[64][20], avs[64];
  int tid = threadIdx.x;
  int r0 = blockIdx.y*64, c0 = blockIdx.x*64;
  for (int i=tid;i<64*20;i+=256){ int r=i/20, k=i-r*20; Ds[r][k] = Dp[(size_t)(r0+r)*20+k]; Bs[r][k] = B1[(size_t)(c0+r)*20+k]; }
  if (tid < 64) avs[tid] = av[c0+tid];
  __syncthreads();
  int tr = tid>>4, tc = tid&15;
  for (int i=0;i<4;i++){
    int r = tr*4+i;
    float4 o;
    float* op = (float*)&o;
    for (int j=0;j<4;j++){
      int c = tc*4+j;
      float s = avs[c];
      for (int k=0;k<20;k++) s += Ds[r][k]*Bs[c][k];
      op[j] = s;
    }
    *(float4*)&out[(size_t)(r0+r)*4096 + c0 + tc*4] = o;
  }
}

extern "C" void kernel_launch(void* const* d_in, const int* in_sizes, int n_in,
                              void* d_out, int out_size, void* d_ws, size_t ws_size,
                              hipStream_t stream)
{
  const int*   char_ids = (const int*)  d_in[0];
  const int*   words    = (const int*)  d_in[1];
  const int*   tags     = (const int*)  d_in[2];
  const int*   wend     = (const int*)  d_in[3];
  const float* word_emb = (const float*)d_in[4];
  const float* tag_emb  = (const float*)d_in[5];
  const float* char_emb = (const float*)d_in[6];
  const float* uni_Wih  = (const float*)d_in[7];
  const float* uni_Whh  = (const float*)d_in[8];
  const float* uni_b    = (const float*)d_in[9];
  const float* ch_W1 = (const float*)d_in[10]; const float* ch_b1 = (const float*)d_in[11];
  const float* ch_W2 = (const float*)d_in[12]; const float* ch_b2 = (const float*)d_in[13];
  const float* bWih0 = (const float*)d_in[14]; const float* bWhh0 = (const float*)d_in[15];
  const float* bb0   = (const float*)d_in[16];
  const float* bWih12= (const float*)d_in[17]; const float* bWhh12= (const float*)d_in[18];
  const float* bb12  = (const float*)d_in[19];
  const float* ah_W1 = (const float*)d_in[20]; const float* ah_b1 = (const float*)d_in[21];
  const float* ah_W2 = (const float*)d_in[22]; const float* ah_b2 = (const float*)d_in[23];
  const float* ad_W1 = (const float*)d_in[24]; const float* ad_b1 = (const float*)d_in[25];
  const float* ad_W2 = (const float*)d_in[26]; const float* ad_b2 = (const float*)d_in[27];
  const float* lh_W1 = (const float*)d_in[28]; const float* lh_b1 = (const float*)d_in[29];
  const float* lh_W2 = (const float*)d_in[30]; const float* lh_b2 = (const float*)d_in[31];
  const float* ld_W1 = (const float*)d_in[32]; const float* ld_b1 = (const float*)d_in[33];
  const float* ld_W2 = (const float*)d_in[34]; const float* ld_b2 = (const float*)d_in[35];
  const float* cl_W1 = (const float*)d_in[36]; const float* cl_b1 = (const float*)d_in[37];
  const float* cl_W2 = (const float*)d_in[38]; const float* cl_b2 = (const float*)d_in[39];
  const float* U1    = (const float*)d_in[40]; const float* u2    = (const float*)d_in[41];
  float* out = (float*)d_out;

  size_t off = 0;
  auto WS = [&](size_t bytes)->char*{ char* p = (char*)d_ws + off; off += (bytes + 255) & ~(size_t)255; return p; };
  float* T5   = (float*)WS((size_t)5000*800*4);
  float* hend = (float*)WS((size_t)4096*200*4);
  float* HW1  = (float*)WS((size_t)4096*400*4);
  float* hch  = (float*)WS((size_t)4096*100*4);
  float* x0   = (float*)WS((size_t)4096*200*4);
  float* xgF  = (float*)WS((size_t)4096*1600*4);
  float* xgB  = (float*)WS((size_t)4096*1600*4);
  float* hA   = (float*)WS((size_t)4096*800*4);
  float* hB   = (float*)WS((size_t)4096*800*4);
  int*   inv  = (int*)  WS((size_t)TC*4);
  float* headH= (float*)WS((size_t)4096*500*4);
  float* Ahd  = (float*)WS((size_t)4096*20*4);
  float* Dp   = (float*)WS((size_t)4096*20*4);
  float* LCin = (float*)WS((size_t)4096*40*4);
  float* B1   = (float*)WS((size_t)4096*20*4);
  float* av   = (float*)WS((size_t)4096*4);
  f16* Abf  = (f16*)WS((size_t)4096*800*2);
  f16* Abf2 = (f16*)WS((size_t)4096*500*2);
  f16* Bbf  = (f16*)WS((size_t)1600*800*2);
  f16* wtU  = (f16*)WS((size_t)200*800*2);
  f16* wtL[6]; for (int i=0;i<6;i++) wtL[i] = (f16*)WS((size_t)400*1600*2);

  auto conv = [&](const float* s, f16* d, int n){
    k_conv<<<dim3((n+255)/256), dim3(256), 0, stream>>>(s, d, n); };
  auto gemm = [&](const f16* A, const f16* B, float* C, const float* bias,
                  int M, int N, int K, int ldc, int coff, int act){
    k_gemm<<<dim3((unsigned)((N+63)/64), (unsigned)((M+63)/64)), dim3(256), 0, stream>>>(A,B,C,bias,M,N,K,ldc,coff,act); };

  // inverse word-end map
  k_fill_inv<<<dim3(TC/256), dim3(256), 0, stream>>>(inv);
  k_set_inv<<<dim3(NW/256), dim3(256), 0, stream>>>(wend, inv);

  // pair-interleaved transposed f16 recurrent weights
  k_trans2<<<dim3((800*200+255)/256), dim3(256), 0, stream>>>(uni_Whh, wtU, 800, 200);
  for (int l=0;l<3;l++) for (int d=0;d<2;d++){
    const float* Wp = (l==0) ? (bWhh0 + (size_t)d*1600*400)
                             : (bWhh12 + (size_t)((l-1)*2+d)*1600*400);
    k_trans2<<<dim3((1600*400+255)/256), dim3(256), 0, stream>>>(Wp, wtL[l*2+d], 1600, 400);
  }

  // char gate table: T5[v] = char_emb[v] @ uni_Wih^T + uni_b
  conv(char_emb, Abf, 5000*200);
  conv(uni_Wih, Bbf, 800*200);
  gemm(Abf, Bbf, T5, uni_b, 5000, 800, 200, 800, 0, 0);

  k_charlstm2<<<dim3(TC/(2*CCH)), dim3(256), 0, stream>>>(T5, char_ids, wtU, inv, hend);

  // char MLP -> h_char
  conv(hend, Abf, 4096*200); conv(ch_W1, Bbf, 400*200);
  gemm(Abf, Bbf, HW1, ch_b1, 4096, 400, 200, 400, 0, 2);
  conv(HW1, Abf, 4096*400); conv(ch_W2, Bbf, 100*400);
  gemm(Abf, Bbf, hch, ch_b2, 4096, 100, 400, 100, 0, 0);

  k_x0<<<dim3(NW), dim3(256), 0, stream>>>(words, tags, word_emb, tag_emb, hch, x0);

  // ----- biLSTM layer 0 -----
  conv(x0, Abf, 4096*200);
  conv(bWih0, Bbf, 1600*200);
  gemm(Abf, Bbf, xgF, bb0, 4096, 1600, 200, 1600, 0, 0);
  conv(bWih0 + (size_t)1600*200, Bbf, 1600*200);
  gemm(Abf, Bbf, xgB, bb0 + 1600, 4096, 1600, 200, 1600, 0, 0);
  k_bilstm2<<<dim3(NW/(2*BCH), 2), dim3(512), 0, stream>>>(xgF, xgB, wtL[0], wtL[1], hA);

  // ----- biLSTM layers 1,2 -----
  float* bufs[2] = { hA, hB };
  for (int l=1;l<3;l++){
    const float* hin = bufs[(l-1)&1];
    float* ho = bufs[l&1];
    conv(hin, Abf, 4096*800);
    conv(bWih12 + (size_t)((l-1)*2+0)*1600*800, Bbf, 1600*800);
    gemm(Abf, Bbf, xgF, bb12 + (size_t)((l-1)*2+0)*1600, 4096, 1600, 800, 1600, 0, 0);
    conv(bWih12 + (size_t)((l-1)*2+1)*1600*800, Bbf, 1600*800);
    gemm(Abf, Bbf, xgB, bb12 + (size_t)((l-1)*2+1)*1600, 4096, 1600, 800, 1600, 0, 0);
    k_bilstm2<<<dim3(NW/(2*BCH), 2), dim3(512), 0, stream>>>(xgF, xgB, wtL[l*2], wtL[l*2+1], ho);
  }
  const float* o2 = bufs[0];  // layer 2 output lands in hA

  // ----- heads -----
  conv(o2, Abf, 4096*800);
  conv(ah_W1, Bbf, 500*800); gemm(Abf, Bbf, headH, ah_b1, 4096, 500, 800, 500, 0, 1);
  conv(headH, Abf2, 4096*500); conv(ah_W2, Bbf, 20*500); gemm(Abf2, Bbf, Ahd, ah_b2, 4096, 20, 500, 20, 0, 0);
  conv(ad_W1, Bbf, 500*800); gemm(Abf, Bbf, headH, ad_b1, 4096, 500, 800, 500, 0, 1);
  conv(headH, Abf2, 4096*500); conv(ad_W2, Bbf, 20*500); gemm(Abf2, Bbf, Dp, ad_b2, 4096, 20, 500, 20, 0, 0);
  conv(lh_W1, Bbf, 200*800); gemm(Abf, Bbf, headH, lh_b1, 4096, 200, 800, 200, 0, 1);
  conv(headH, Abf2, 4096*200); conv(lh_W2, Bbf, 20*200); gemm(Abf2, Bbf, LCin, lh_b2, 4096, 20, 200, 40, 0, 0);
  conv(ld_W1, Bbf, 200*800); gemm(Abf, Bbf, headH, ld_b1, 4096, 200, 800, 200, 0, 1);
  conv(headH, Abf2, 4096*200); conv(ld_W2, Bbf, 20*200); gemm(Abf2, Bbf, LCin, ld_b2, 4096, 20, 200, 40, 20, 0);
  conv(LCin, Abf2, 4096*40); conv(cl_W1, Bbf, 60*40); gemm(Abf2, Bbf, headH, cl_b1, 4096, 60, 40, 60, 0, 1);
  conv(headH, Abf2, 4096*60); conv(cl_W2, Bbf, 40*60);
  gemm(Abf2, Bbf, out + (size_t)4096*4096, cl_b2, 4096, 40, 60, 40, 0, 0);

  // ----- biaffine adjacency (transposed) -----
  k_b1av<<<dim3(NW/256), dim3(256), 0, stream>>>(Ahd, U1, u2, B1, av);
  k_adjT<<<dim3(64,64), dim3(256), 0, stream>>>(Dp, B1, av, out);

  (void)in_sizes; (void)n_in; (void)out_size; (void)ws_size;
}

// Round 9
// 3197.511 us; speedup vs baseline: 3.0671x; 1.3505x over previous
//
#include <hip/hip_runtime.h>
#include <math.h>

typedef _Float16 f16;
typedef __attribute__((ext_vector_type(2))) _Float16 h2;
typedef __attribute__((ext_vector_type(4))) _Float16 f16x4;
typedef __attribute__((ext_vector_type(8))) _Float16 f16x8;
typedef __attribute__((ext_vector_type(4))) float f32x4;

#define NW 4096
#define TC 32768
#define CCH 32
#define CWU 36
#define BCH 16
#define BWU 36

static __device__ __forceinline__ float sigm(float x){ return 1.0f/(1.0f + expf(-x)); }

#if __has_builtin(__builtin_amdgcn_fdot2)
static __device__ __forceinline__ float DOT2(h2 w, h2 h, float acc){
  return __builtin_amdgcn_fdot2(w, h, acc, false);
}
#else
static __device__ __forceinline__ float DOT2(h2 w, h2 h, float acc){
  return fmaf((float)w[0], (float)h[0], fmaf((float)w[1], (float)h[1], acc));
}
#endif

// ---------- elementwise helpers ----------
__global__ void k_conv(const float* __restrict__ s, f16* __restrict__ d, int n){
  int i = blockIdx.x*256 + threadIdx.x;
  if (i < n) d[i] = (f16)s[i];
}

// W [G][H] f32 -> pair-interleaved: o[((k>>1)*G + g)*2 + (k&1)] = W[g][k]
__global__ void k_trans2(const float* __restrict__ W, f16* __restrict__ o, int G, int H){
  int i = blockIdx.x*256 + threadIdx.x;
  if (i < G*H){ int g = i/H, k = i - g*H; o[((size_t)(k>>1)*G + g)*2 + (k&1)] = (f16)W[i]; }
}

__global__ void k_fill_inv(int* inv){ int i = blockIdx.x*256 + threadIdx.x; if (i < TC) inv[i] = -1; }
__global__ void k_set_inv(const int* __restrict__ we, int* __restrict__ inv){
  int i = blockIdx.x*256 + threadIdx.x; if (i < NW) inv[we[i]] = i;
}

// ---------- generic f16 MFMA GEMM: C[M,N] = act(A[M,K] @ B[N,K]^T + bias[N]) ----------
__global__ __launch_bounds__(256) void k_gemm(
    const f16* __restrict__ A, const f16* __restrict__ B, float* __restrict__ C,
    const float* __restrict__ bias, int M, int N, int K, int ldc, int coff, int act)
{
  __shared__ f16 As[64][40];
  __shared__ f16 Bs[64][40];
  const int tid = threadIdx.x;
  const int row0 = blockIdx.y*64, col0 = blockIdx.x*64;
  const int w = tid>>6, lane = tid&63, wr = w>>1, wc = w&1;
  const int lr = tid>>2, lk = (tid&3)*8;
  f32x4 acc[2][2];
  for (int a=0;a<2;a++) for(int b=0;b<2;b++) acc[a][b] = (f32x4){0.f,0.f,0.f,0.f};
  const int nkt = (K+31)>>5;
  for (int kt=0; kt<nkt; ++kt){
    const int kb = (kt<<5) + lk;
    {
      int gr = row0 + lr;
      if (gr < M && kb + 8 <= K){
        f16x4 v0 = *(const f16x4*)(A + (size_t)gr*K + kb);
        f16x4 v1 = *(const f16x4*)(A + (size_t)gr*K + kb + 4);
        *(f16x4*)&As[lr][lk] = v0; *(f16x4*)&As[lr][lk+4] = v1;
      } else {
        for (int j=0;j<8;j++){ int kk = kb+j; As[lr][lk+j] = (gr<M && kk<K) ? A[(size_t)gr*K+kk] : (f16)0.f; }
      }
      int gc = col0 + lr;
      if (gc < N && kb + 8 <= K){
        f16x4 v0 = *(const f16x4*)(B + (size_t)gc*K + kb);
        f16x4 v1 = *(const f16x4*)(B + (size_t)gc*K + kb + 4);
        *(f16x4*)&Bs[lr][lk] = v0; *(f16x4*)&Bs[lr][lk+4] = v1;
      } else {
        for (int j=0;j<8;j++){ int kk = kb+j; Bs[lr][lk+j] = (gc<N && kk<K) ? B[(size_t)gc*K+kk] : (f16)0.f; }
      }
    }
    __syncthreads();
    #pragma unroll
    for (int kk=0; kk<32; kk+=16){
      const int kq = kk + (lane>>4)*4;
      f16x4 af[2], bf[2];
      af[0] = *(const f16x4*)&As[wr*32 +      (lane&15)][kq];
      af[1] = *(const f16x4*)&As[wr*32 + 16 + (lane&15)][kq];
      bf[0] = *(const f16x4*)&Bs[wc*32 +      (lane&15)][kq];
      bf[1] = *(const f16x4*)&Bs[wc*32 + 16 + (lane&15)][kq];
      #pragma unroll
      for (int mt=0;mt<2;mt++)
        #pragma unroll
        for (int nt=0;nt<2;nt++)
          acc[mt][nt] = __builtin_amdgcn_mfma_f32_16x16x16f16(af[mt], bf[nt], acc[mt][nt], 0,0,0);
    }
    __syncthreads();
  }
  for (int mt=0;mt<2;mt++) for (int nt=0;nt<2;nt++){
    int c = col0 + wc*32 + nt*16 + (lane&15);
    if (c >= N) continue;
    float bv = bias ? bias[c] : 0.f;
    for (int j=0;j<4;j++){
      int r = row0 + wr*32 + mt*16 + (lane>>4)*4 + j;
      if (r >= M) continue;
      float v = acc[mt][nt][j] + bv;
      if (act==1) v = v>0.f ? v : 0.f;
      else if (act==2) v = v>0.f ? v : 0.01f*v;
      C[(size_t)r*ldc + coff + c] = v;
    }
  }
}

// ---------- chunked char LSTM v2: R=2 chunks/block, dot2, f16 h in LDS ----------
__global__ __launch_bounds__(256) void k_charlstm2(
    const float* __restrict__ T5, const int* __restrict__ cid,
    const f16* __restrict__ WT2, const int* __restrict__ inv, float* __restrict__ hend)
{
  __shared__ f16 hsh[2][200];
  __shared__ float gs[2][800];
  const int tid = threadIdx.x;
  const int s0 = blockIdx.x * (2*CCH);
  const int s1 = s0 + CCH;
  for (int i=tid;i<200;i+=256){ hsh[0][i]=(f16)0.f; hsh[1][i]=(f16)0.f; }
  __syncthreads();
  const int g0 = tid*4;
  const bool on = (tid < 200);
  float c0r = 0.f, c1r = 0.f;
  for (int s=-CWU; s<CCH; ++s){
    const int t0 = s0 + s, t1 = s1 + s;
    const bool act0 = t0 >= 0, act1 = t1 >= 0;
    if (on){
      const int t0c = act0 ? t0 : 0, t1c = act1 ? t1 : 0;
      float4 a0 = *(const float4*)&T5[(size_t)cid[t0c]*800 + g0];
      float4 a1 = *(const float4*)&T5[(size_t)cid[t1c]*800 + g0];
      const f16* wp = WT2 + g0*2;
      #pragma unroll 4
      for (int k2=0;k2<100;k2++){
        f16x8 wv = *(const f16x8*)wp; wp += 1600;
        h2 h0 = *(const h2*)&hsh[0][k2*2];
        h2 h1 = *(const h2*)&hsh[1][k2*2];
        h2 w0 = {wv[0],wv[1]}, w1 = {wv[2],wv[3]}, w2 = {wv[4],wv[5]}, w3 = {wv[6],wv[7]};
        a0.x = DOT2(w0,h0,a0.x); a0.y = DOT2(w1,h0,a0.y); a0.z = DOT2(w2,h0,a0.z); a0.w = DOT2(w3,h0,a0.w);
        a1.x = DOT2(w0,h1,a1.x); a1.y = DOT2(w1,h1,a1.y); a1.z = DOT2(w2,h1,a1.z); a1.w = DOT2(w3,h1,a1.w);
      }
      *(float4*)&gs[0][g0] = a0;
      *(float4*)&gs[1][g0] = a1;
    }
    __syncthreads();
    if (on){
      if (act0){
        float c = sigm(gs[0][200+tid])*c0r + sigm(gs[0][tid])*tanhf(gs[0][400+tid]);
        c0r = c;
        float h = sigm(gs[0][600+tid])*tanhf(c);
        hsh[0][tid] = (f16)h;
        if (s >= 0){ int wi = inv[t0]; if (wi >= 0) hend[(size_t)wi*200 + tid] = h; }
      }
      if (act1){
        float c = sigm(gs[1][200+tid])*c1r + sigm(gs[1][tid])*tanhf(gs[1][400+tid]);
        c1r = c;
        float h = sigm(gs[1][600+tid])*tanhf(c);
        hsh[1][tid] = (f16)h;
        if (s >= 0){ int wi = inv[t1]; if (wi >= 0) hend[(size_t)wi*200 + tid] = h; }
      }
    }
    __syncthreads();
  }
}

// ---------- chunked biLSTM v2: R=2 chunks/block, dot2, f16 h in LDS ----------
__global__ __launch_bounds__(512) void k_bilstm2(
    const float* __restrict__ xgF, const float* __restrict__ xgB,
    const f16* __restrict__ WT2F, const f16* __restrict__ WT2B,
    float* __restrict__ hout)
{
  __shared__ f16 hsh[2][400];
  __shared__ float gs[2][1600];
  const int tid = threadIdx.x;
  const int d = blockIdx.y;
  const float* __restrict__ xg = d ? xgB : xgF;
  const f16* __restrict__ W2 = d ? WT2B : WT2F;
  const int s0 = blockIdx.x * (2*BCH);
  const int s1 = s0 + BCH;
  for (int i=tid;i<400;i+=512){ hsh[0][i]=(f16)0.f; hsh[1][i]=(f16)0.f; }
  __syncthreads();
  const int g0 = tid*4;
  const bool on = (tid < 400);
  float c0r = 0.f, c1r = 0.f;
  for (int s=-BWU; s<BCH; ++s){
    const int p0 = s0 + s, p1 = s1 + s;
    const bool act0 = p0 >= 0, act1 = p1 >= 0;
    const int q0 = d ? (NW-1-p0) : p0;
    const int q1 = d ? (NW-1-p1) : p1;
    if (on){
      const int q0c = act0 ? q0 : 0, q1c = act1 ? q1 : 0;
      float4 a0 = *(const float4*)&xg[(size_t)q0c*1600 + g0];
      float4 a1 = *(const float4*)&xg[(size_t)q1c*1600 + g0];
      const f16* wp = W2 + g0*2;
      #pragma unroll 4
      for (int k2=0;k2<200;k2++){
        f16x8 wv = *(const f16x8*)wp; wp += 3200;
        h2 h0 = *(const h2*)&hsh[0][k2*2];
        h2 h1 = *(const h2*)&hsh[1][k2*2];
        h2 w0 = {wv[0],wv[1]}, w1 = {wv[2],wv[3]}, w2 = {wv[4],wv[5]}, w3 = {wv[6],wv[7]};
        a0.x = DOT2(w0,h0,a0.x); a0.y = DOT2(w1,h0,a0.y); a0.z = DOT2(w2,h0,a0.z); a0.w = DOT2(w3,h0,a0.w);
        a1.x = DOT2(w0,h1,a1.x); a1.y = DOT2(w1,h1,a1.y); a1.z = DOT2(w2,h1,a1.z); a1.w = DOT2(w3,h1,a1.w);
      }
      *(float4*)&gs[0][g0] = a0;
      *(float4*)&gs[1][g0] = a1;
    }
    __syncthreads();
    if (on){
      if (act0){
        float c = sigm(gs[0][400+tid])*c0r + sigm(gs[0][tid])*tanhf(gs[0][800+tid]);
        c0r = c;
        float h = sigm(gs[0][1200+tid])*tanhf(c);
        hsh[0][tid] = (f16)h;
        if (s >= 0) hout[(size_t)q0*800 + d*400 + tid] = h;
      }
      if (act1){
        float c = sigm(gs[1][400+tid])*c1r + sigm(gs[1][tid])*tanhf(gs[1][800+tid]);
        c1r = c;
        float h = sigm(gs[1][1200+tid])*tanhf(c);
        hsh[1][tid] = (f16)h;
        if (s >= 0) hout[(size_t)q1*800 + d*400 + tid] = h;
      }
    }
    __syncthreads();
  }
}

// ---------- x0 = [word_emb[words] + h_char , tag_emb[tags]] ----------
__global__ void k_x0(const int* __restrict__ words, const int* __restrict__ tags,
                     const float* __restrict__ wemb, const float* __restrict__ temb,
                     const float* __restrict__ hch, float* __restrict__ x0)
{
  int i = blockIdx.x, tid = threadIdx.x;
  if (tid < 100) x0[(size_t)i*200 + tid] = wemb[(size_t)words[i]*100 + tid] + hch[(size_t)i*100 + tid];
  else if (tid < 200) x0[(size_t)i*200 + tid] = temb[(size_t)tags[i]*100 + (tid-100)];
}

// ---------- B1 = A@U1, av = A@u2^T ----------
__global__ __launch_bounds__(256) void k_b1av(const float* __restrict__ Ah, const float* __restrict__ U1,
    const float* __restrict__ u2, float* __restrict__ B1, float* __restrict__ av)
{
  __shared__ float u[400], uu[20];
  int tid = threadIdx.x;
  for (int i=tid;i<400;i+=256) u[i] = U1[i];
  if (tid < 20) uu[tid] = u2[tid];
  __syncthreads();
  int i = blockIdx.x*256 + tid;
  float a[20];
  for (int k=0;k<20;k++) a[k] = Ah[(size_t)i*20 + k];
  float s2 = 0.f;
  for (int k=0;k<20;k++) s2 += a[k]*uu[k];
  av[i] = s2;
  for (int j=0;j<20;j++){
    float s = 0.f;
    for (int k=0;k<20;k++) s += a[k]*u[k*20+j];
    B1[(size_t)i*20 + j] = s;
  }
}

// ---------- out[r,c] = adj.T = dot20(Dp[r], B1[c]) + av[c] ----------
__global__ __launch_bounds__(256) void k_adjT(const float* __restrict__ Dp, const float* __restrict__ B1,
    const float* __restrict__ av, float* __restrict__ out)
{
  __shared__ float Ds[64][20], Bs[64][20], avs[64];
  int tid = threadIdx.x;
  int r0 = blockIdx.y*64, c0 = blockIdx.x*64;
  for (int i=tid;i<64*20;i+=256){ int r=i/20, k=i-r*20; Ds[r][k] = Dp[(size_t)(r0+r)*20+k]; Bs[r][k] = B1[(size_t)(c0+r)*20+k]; }
  if (tid < 64) avs[tid] = av[c0+tid];
  __syncthreads();
  int tr = tid>>4, tc = tid&15;
  for (int i=0;i<4;i++){
    int r = tr*4+i;
    float4 o;
    float* op = (float*)&o;
    for (int j=0;j<4;j++){
      int c = tc*4+j;
      float s = avs[c];
      for (int k=0;k<20;k++) s += Ds[r][k]*Bs[c][k];
      op[j] = s;
    }
    *(float4*)&out[(size_t)(r0+r)*4096 + c0 + tc*4] = o;
  }
}

extern "C" void kernel_launch(void* const* d_in, const int* in_sizes, int n_in,
                              void* d_out, int out_size, void* d_ws, size_t ws_size,
                              hipStream_t stream)
{
  const int*   char_ids = (const int*)  d_in[0];
  const int*   words    = (const int*)  d_in[1];
  const int*   tags     = (const int*)  d_in[2];
  const int*   wend     = (const int*)  d_in[3];
  const float* word_emb = (const float*)d_in[4];
  const float* tag_emb  = (const float*)d_in[5];
  const float* char_emb = (const float*)d_in[6];
  const float* uni_Wih  = (const float*)d_in[7];
  const float* uni_Whh  = (const float*)d_in[8];
  const float* uni_b    = (const float*)d_in[9];
  const float* ch_W1 = (const float*)d_in[10]; const float* ch_b1 = (const float*)d_in[11];
  const float* ch_W2 = (const float*)d_in[12]; const float* ch_b2 = (const float*)d_in[13];
  const float* bWih0 = (const float*)d_in[14]; const float* bWhh0 = (const float*)d_in[15];
  const float* bb0   = (const float*)d_in[16];
  const float* bWih12= (const float*)d_in[17]; const float* bWhh12= (const float*)d_in[18];
  const float* bb12  = (const float*)d_in[19];
  const float* ah_W1 = (const float*)d_in[20]; const float* ah_b1 = (const float*)d_in[21];
  const float* ah_W2 = (const float*)d_in[22]; const float* ah_b2 = (const float*)d_in[23];
  const float* ad_W1 = (const float*)d_in[24]; const float* ad_b1 = (const float*)d_in[25];
  const float* ad_W2 = (const float*)d_in[26]; const float* ad_b2 = (const float*)d_in[27];
  const float* lh_W1 = (const float*)d_in[28]; const float* lh_b1 = (const float*)d_in[29];
  const float* lh_W2 = (const float*)d_in[30]; const float* lh_b2 = (const float*)d_in[31];
  const float* ld_W1 = (const float*)d_in[32]; const float* ld_b1 = (const float*)d_in[33];
  const float* ld_W2 = (const float*)d_in[34]; const float* ld_b2 = (const float*)d_in[35];
  const float* cl_W1 = (const float*)d_in[36]; const float* cl_b1 = (const float*)d_in[37];
  const float* cl_W2 = (const float*)d_in[38]; const float* cl_b2 = (const float*)d_in[39];
  const float* U1    = (const float*)d_in[40]; const float* u2    = (const float*)d_in[41];
  float* out = (float*)d_out;

  size_t off = 0;
  auto WS = [&](size_t bytes)->char*{ char* p = (char*)d_ws + off; off += (bytes + 255) & ~(size_t)255; return p; };
  float* T5   = (float*)WS((size_t)5000*800*4);
  float* hend = (float*)WS((size_t)4096*200*4);
  float* HW1  = (float*)WS((size_t)4096*400*4);
  float* hch  = (float*)WS((size_t)4096*100*4);
  float* x0   = (float*)WS((size_t)4096*200*4);
  float* xgF  = (float*)WS((size_t)4096*1600*4);
  float* xgB  = (float*)WS((size_t)4096*1600*4);
  float* hA   = (float*)WS((size_t)4096*800*4);
  float* hB   = (float*)WS((size_t)4096*800*4);
  int*   inv  = (int*)  WS((size_t)TC*4);
  float* headH= (float*)WS((size_t)4096*500*4);
  float* Ahd  = (float*)WS((size_t)4096*20*4);
  float* Dp   = (float*)WS((size_t)4096*20*4);
  float* LCin = (float*)WS((size_t)4096*40*4);
  float* B1   = (float*)WS((size_t)4096*20*4);
  float* av   = (float*)WS((size_t)4096*4);
  f16* Abf  = (f16*)WS((size_t)4096*800*2);
  f16* Abf2 = (f16*)WS((size_t)4096*500*2);
  f16* Bbf  = (f16*)WS((size_t)1600*800*2);
  f16* wtU  = (f16*)WS((size_t)200*800*2);
  f16* wtL[6]; for (int i=0;i<6;i++) wtL[i] = (f16*)WS((size_t)400*1600*2);

  auto conv = [&](const float* s, f16* d, int n){
    k_conv<<<dim3((n+255)/256), dim3(256), 0, stream>>>(s, d, n); };
  auto gemm = [&](const f16* A, const f16* B, float* C, const float* bias,
                  int M, int N, int K, int ldc, int coff, int act){
    k_gemm<<<dim3((unsigned)((N+63)/64), (unsigned)((M+63)/64)), dim3(256), 0, stream>>>(A,B,C,bias,M,N,K,ldc,coff,act); };

  // inverse word-end map
  k_fill_inv<<<dim3(TC/256), dim3(256), 0, stream>>>(inv);
  k_set_inv<<<dim3(NW/256), dim3(256), 0, stream>>>(wend, inv);

  // pair-interleaved transposed f16 recurrent weights
  k_trans2<<<dim3((800*200+255)/256), dim3(256), 0, stream>>>(uni_Whh, wtU, 800, 200);
  for (int l=0;l<3;l++) for (int d=0;d<2;d++){
    const float* Wp = (l==0) ? (bWhh0 + (size_t)d*1600*400)
                             : (bWhh12 + (size_t)((l-1)*2+d)*1600*400);
    k_trans2<<<dim3((1600*400+255)/256), dim3(256), 0, stream>>>(Wp, wtL[l*2+d], 1600, 400);
  }

  // char gate table: T5[v] = char_emb[v] @ uni_Wih^T + uni_b
  conv(char_emb, Abf, 5000*200);
  conv(uni_Wih, Bbf, 800*200);
  gemm(Abf, Bbf, T5, uni_b, 5000, 800, 200, 800, 0, 0);

  k_charlstm2<<<dim3(TC/(2*CCH)), dim3(256), 0, stream>>>(T5, char_ids, wtU, inv, hend);

  // char MLP -> h_char
  conv(hend, Abf, 4096*200); conv(ch_W1, Bbf, 400*200);
  gemm(Abf, Bbf, HW1, ch_b1, 4096, 400, 200, 400, 0, 2);
  conv(HW1, Abf, 4096*400); conv(ch_W2, Bbf, 100*400);
  gemm(Abf, Bbf, hch, ch_b2, 4096, 100, 400, 100, 0, 0);

  k_x0<<<dim3(NW), dim3(256), 0, stream>>>(words, tags, word_emb, tag_emb, hch, x0);

  // ----- biLSTM layer 0 -----
  conv(x0, Abf, 4096*200);
  conv(bWih0, Bbf, 1600*200);
  gemm(Abf, Bbf, xgF, bb0, 4096, 1600, 200, 1600, 0, 0);
  conv(bWih0 + (size_t)1600*200, Bbf, 1600*200);
  gemm(Abf, Bbf, xgB, bb0 + 1600, 4096, 1600, 200, 1600, 0, 0);
  k_bilstm2<<<dim3(NW/(2*BCH), 2), dim3(512), 0, stream>>>(xgF, xgB, wtL[0], wtL[1], hA);

  // ----- biLSTM layers 1,2 -----
  float* bufs[2] = { hA, hB };
  for (int l=1;l<3;l++){
    const float* hin = bufs[(l-1)&1];
    float* ho = bufs[l&1];
    conv(hin, Abf, 4096*800);
    conv(bWih12 + (size_t)((l-1)*2+0)*1600*800, Bbf, 1600*800);
    gemm(Abf, Bbf, xgF, bb12 + (size_t)((l-1)*2+0)*1600, 4096, 1600, 800, 1600, 0, 0);
    conv(bWih12 + (size_t)((l-1)*2+1)*1600*800, Bbf, 1600*800);
    gemm(Abf, Bbf, xgB, bb12 + (size_t)((l-1)*2+1)*1600, 4096, 1600, 800, 1600, 0, 0);
    k_bilstm2<<<dim3(NW/(2*BCH), 2), dim3(512), 0, stream>>>(xgF, xgB, wtL[l*2], wtL[l*2+1], ho);
  }
  const float* o2 = bufs[0];  // layer 2 output lands in hA

  // ----- heads -----
  conv(o2, Abf, 4096*800);
  conv(ah_W1, Bbf, 500*800); gemm(Abf, Bbf, headH, ah_b1, 4096, 500, 800, 500, 0, 1);
  conv(headH, Abf2, 4096*500); conv(ah_W2, Bbf, 20*500); gemm(Abf2, Bbf, Ahd, ah_b2, 4096, 20, 500, 20, 0, 0);
  conv(ad_W1, Bbf, 500*800); gemm(Abf, Bbf, headH, ad_b1, 4096, 500, 800, 500, 0, 1);
  conv(headH, Abf2, 4096*500); conv(ad_W2, Bbf, 20*500); gemm(Abf2, Bbf, Dp, ad_b2, 4096, 20, 500, 20, 0, 0);
  conv(lh_W1, Bbf, 200*800); gemm(Abf, Bbf, headH, lh_b1, 4096, 200, 800, 200, 0, 1);
  conv(headH, Abf2, 4096*200); conv(lh_W2, Bbf, 20*200); gemm(Abf2, Bbf, LCin, lh_b2, 4096, 20, 200, 40, 0, 0);
  conv(ld_W1, Bbf, 200*800); gemm(Abf, Bbf, headH, ld_b1, 4096, 200, 800, 200, 0, 1);
  conv(headH, Abf2, 4096*200); conv(ld_W2, Bbf, 20*200); gemm(Abf2, Bbf, LCin, ld_b2, 4096, 20, 200, 40, 20, 0);
  conv(LCin, Abf2, 4096*40); conv(cl_W1, Bbf, 60*40); gemm(Abf2, Bbf, headH, cl_b1, 4096, 60, 40, 60, 0, 1);
  conv(headH, Abf2, 4096*60); conv(cl_W2, Bbf, 40*60);
  gemm(Abf2, Bbf, out + (size_t)4096*4096, cl_b2, 4096, 40, 60, 40, 0, 0);

  // ----- biaffine adjacency (transposed) -----
  k_b1av<<<dim3(NW/256), dim3(256), 0, stream>>>(Ahd, U1, u2, B1, av);
  k_adjT<<<dim3(64,64), dim3(256), 0, stream>>>(Dp, B1, av, out);

  (void)in_sizes; (void)n_in; (void)out_size; (void)ws_size;
}